// Round 13
// baseline (2376.351 us; speedup 1.0000x reference)
//
#include <hip/hip_runtime.h>
#include <hip/hip_bf16.h>

#define NFEAT 256
#define HID 64
#define NCLASS 40
#define NUM_LAYERS 3

// ---------------------------------------------------------------------------
// lin1: h = relu(x @ w1.T + b1)   x:[N,256] w1:[64,256] -> h:[N,64]
// ---------------------------------------------------------------------------
__global__ __launch_bounds__(256) void k_lin1(
    const float* __restrict__ x, const float* __restrict__ w1,
    const float* __restrict__ b1, float* __restrict__ h, int n_nodes)
{
    __shared__ float xs[8][NFEAT];     // 8 KB
    __shared__ float part[4][8][HID];  // 8 KB
    const int tid  = threadIdx.x;
    const int wave = tid >> 6;
    const int lane = tid & 63;

    float wreg[64];
#pragma unroll
    for (int k = 0; k < 64; k += 4) {
        float4 v = *reinterpret_cast<const float4*>(&w1[lane * NFEAT + wave * 64 + k]);
        wreg[k] = v.x; wreg[k + 1] = v.y; wreg[k + 2] = v.z; wreg[k + 3] = v.w;
    }

    const int nbatch = (n_nodes + 7) >> 3;
    for (int batch = blockIdx.x; batch < nbatch; batch += gridDim.x) {
        const int n0 = batch * 8;
        {
            const float4* xg = reinterpret_cast<const float4*>(x + (size_t)n0 * NFEAT);
            float4* xsv = reinterpret_cast<float4*>(&xs[0][0]);
#pragma unroll
            for (int i = 0; i < 2; ++i) {
                int idx  = tid + i * 256;
                int node = n0 + (idx >> 6);
                xsv[idx] = (node < n_nodes) ? xg[idx] : make_float4(0.f, 0.f, 0.f, 0.f);
            }
        }
        __syncthreads();
        for (int nl = 0; nl < 8; ++nl) {
            const float4* xrow = reinterpret_cast<const float4*>(&xs[nl][wave * 64]);
            float a0 = 0.f, a1 = 0.f, a2 = 0.f, a3 = 0.f;
#pragma unroll
            for (int kq = 0; kq < 16; ++kq) {
                float4 v = xrow[kq];
                a0 = fmaf(v.x, wreg[4 * kq + 0], a0);
                a1 = fmaf(v.y, wreg[4 * kq + 1], a1);
                a2 = fmaf(v.z, wreg[4 * kq + 2], a2);
                a3 = fmaf(v.w, wreg[4 * kq + 3], a3);
            }
            part[wave][nl][lane] = (a0 + a1) + (a2 + a3);
        }
        __syncthreads();
#pragma unroll
        for (int i = 0; i < 2; ++i) {
            int o = tid + i * 256;
            int nl = o >> 6, j = o & 63;
            int node = n0 + nl;
            if (node < n_nodes) {
                float v = part[0][nl][j] + part[1][nl][j] + part[2][nl][j] + part[3][nl][j]
                          + b1[j];
                h[(size_t)node * HID + j] = fmaxf(v, 0.f);
            }
        }
        __syncthreads();
    }
}

// ---------------------------------------------------------------------------
// CSR build: histogram of dst, exclusive scan, fill col_src  (int32 inputs)
// ---------------------------------------------------------------------------
__global__ void k_hist(const int* __restrict__ ei, int* __restrict__ cnt, int E)
{
    int i = blockIdx.x * blockDim.x + threadIdx.x;
    if (i < E) atomicAdd(&cnt[ei[E + i]], 1);
}

#define SCAN_C 2048
__global__ __launch_bounds__(512) void k_scan1(const int* __restrict__ cnt,
                                               int* __restrict__ btot, int n)
{
    __shared__ int sd[512];
    int b = blockIdx.x, t = threadIdx.x;
    int base = b * SCAN_C + t * 4;
    int s = 0;
#pragma unroll
    for (int i = 0; i < 4; ++i) { int idx = base + i; if (idx < n) s += cnt[idx]; }
    sd[t] = s; __syncthreads();
    for (int off = 256; off > 0; off >>= 1) {
        if (t < off) sd[t] += sd[t + off];
        __syncthreads();
    }
    if (t == 0) btot[b] = sd[0];
}

__global__ __launch_bounds__(1024) void k_scan2(int* __restrict__ btot, int nb)
{
    __shared__ int sd[1024];
    int t = threadIdx.x;
    int v = (t < nb) ? btot[t] : 0;
    sd[t] = v; __syncthreads();
    for (int off = 1; off < 1024; off <<= 1) {
        int x = sd[t];
        int add = (t >= off) ? sd[t - off] : 0;
        __syncthreads();
        sd[t] = x + add;
        __syncthreads();
    }
    if (t < nb) btot[t] = sd[t] - v;  // exclusive
}

__global__ __launch_bounds__(512) void k_scan3(const int* __restrict__ cnt,
                                               const int* __restrict__ btot,
                                               int* __restrict__ row_ptr,
                                               int* __restrict__ cursor, int n)
{
    __shared__ int sth[512];
    int b = blockIdx.x, t = threadIdx.x;
    int base = b * SCAN_C + t * 4;
    int v[4]; int s = 0;
#pragma unroll
    for (int i = 0; i < 4; ++i) { int idx = base + i; v[i] = (idx < n) ? cnt[idx] : 0; s += v[i]; }
    sth[t] = s; __syncthreads();
    int mine = s;
    for (int off = 1; off < 512; off <<= 1) {
        int x = sth[t];
        int add = (t >= off) ? sth[t - off] : 0;
        __syncthreads();
        sth[t] = x + add;
        __syncthreads();
    }
    int carry = btot[b] + (sth[t] - mine);
#pragma unroll
    for (int i = 0; i < 4; ++i) {
        int idx = base + i;
        if (idx < n) {
            row_ptr[idx] = carry;
            cursor[idx]  = carry;
            carry += v[i];
            if (idx == n - 1) row_ptr[n] = carry;  // = E
        }
    }
}

__global__ void k_fill(const int* __restrict__ ei, int* __restrict__ cursor,
                       int* __restrict__ col_src, int E)
{
    int i = blockIdx.x * blockDim.x + threadIdx.x;
    if (i < E) {
        int dst = ei[E + i];
        int p = atomicAdd(&cursor[dst], 1);
        col_src[p] = ei[i];
    }
}

// ---------------------------------------------------------------------------
// aggregation: ah[n] = sum_{e: dst=n} h[src[e]]   (wave per node, lane = feat)
// ---------------------------------------------------------------------------
__global__ __launch_bounds__(256) void k_agg(
    const float* __restrict__ h, const int* __restrict__ row_ptr,
    const int* __restrict__ col_src, float* __restrict__ ah, int n_nodes)
{
    int wid    = (blockIdx.x * blockDim.x + threadIdx.x) >> 6;
    int lane   = threadIdx.x & 63;
    int nwaves = (gridDim.x * blockDim.x) >> 6;
    for (int node = wid; node < n_nodes; node += nwaves) {
        int e0 = row_ptr[node], e1 = row_ptr[node + 1];
        float acc = 0.f;
        int e = e0;
        for (; e + 4 <= e1; e += 4) {
            int s0 = col_src[e], s1 = col_src[e + 1], s2 = col_src[e + 2], s3 = col_src[e + 3];
            float v0 = h[(size_t)s0 * HID + lane];
            float v1 = h[(size_t)s1 * HID + lane];
            float v2 = h[(size_t)s2 * HID + lane];
            float v3 = h[(size_t)s3 * HID + lane];
            acc += (v0 + v1) + (v2 + v3);
        }
        for (; e < e1; ++e) acc += h[(size_t)col_src[e] * HID + lane];
        ah[(size_t)node * HID + lane] = acc;
    }
}

// ---------------------------------------------------------------------------
// Wic[l][j][k] = sum_m w_ih[j][m] * gg_w[l][k][m]
// (agg = segsum(h) @ gg_w[l]  =>  gi = segsum(h) @ (gg_w[l] @ w_ih.T))
// ---------------------------------------------------------------------------
__global__ void k_wic(const float* __restrict__ gg_w, const float* __restrict__ w_ih,
                      float* __restrict__ Wic)
{
    int idx = blockIdx.x * blockDim.x + threadIdx.x;
    if (idx < NUM_LAYERS * 192 * 64) {
        int l = idx / (192 * 64);
        int j = (idx / 64) % 192;
        int k = idx % 64;
        const float* gw = gg_w + ((size_t)l * 64 + k) * 64;
        const float* wi = w_ih + (size_t)j * 64;
        float acc = 0.f;
#pragma unroll 4
        for (int m = 0; m < 64; ++m) acc = fmaf(wi[m], gw[m], acc);
        Wic[idx] = acc;
    }
}

// ---------------------------------------------------------------------------
// fused GRU v6 — GEMM-style tile, spill-proof by construction.
// Block = 1024 thr = 16 waves over a 64-node tile. lane = node (within tile),
// wave wid handles feats f = wid*4..wid*4+3 (16 waves x 4 = all 64 feats).
// - ah/h tiles staged in padded LDS [64][65]: read bank = (lane+k)%32 ->
//   2-way aliasing = free (m136). SHARED tile (unlike r12's per-thread park),
//   so 8 ds_read_b32 per k-quad serve 96 FMAs (12:1).
// - weights via wave-uniform s_load (f, kb wave-uniform -> scalar pipe).
// - per-thread state: acc[4][6] + 8 staged floats ~ 50 VGPR, static indices
//   only -> fits ANY heuristic cap; no spill possible (r7-r12 lesson: the
//   allocator never keeps 64-float arrays resident, so don't ask it to).
// - gate math inline (hold from h tile in LDS); out staged in LDS, coalesced
//   float4 write-back. No gi round-trip (saves 308 MB traffic/layer).
// 49.9 KB LDS -> 2 blocks/CU (thread-limited). VALU floor 62 us/layer.
// ---------------------------------------------------------------------------
#define G6_THREADS 1024
__global__ __launch_bounds__(G6_THREADS) void k_gru6(
    const float* __restrict__ ah, float* __restrict__ h,
    const float* __restrict__ Wic, const float* __restrict__ whh,
    const float* __restrict__ b_ih, const float* __restrict__ b_hh, int n_nodes)
{
    __shared__ float a_lds[64][65];
    __shared__ float h_lds[64][65];
    __shared__ float o_lds[64][65];

    const int tid  = threadIdx.x;
    const int wid  = tid >> 6;
    const int lane = tid & 63;
    const int n0   = blockIdx.x * 64;

    // stage 64 ah rows + 64 h rows (2048 float4, 2 per thread, coalesced)
#pragma unroll
    for (int i = 0; i < 2; ++i) {
        int fi  = tid + i * G6_THREADS;  // 0..2047
        int arr = fi >> 10;              // 0: ah, 1: h
        int e   = fi & 1023;
        int r   = e >> 4;
        int c   = (e & 15) * 4;
        int node = n0 + r;
        float4 v = make_float4(0.f, 0.f, 0.f, 0.f);
        if (node < n_nodes) {
            const float4* src = reinterpret_cast<const float4*>(
                (arr == 0 ? ah : h) + (size_t)node * HID);
            v = src[e & 15];
        }
        float* dst = (arr == 0) ? &a_lds[r][c] : &h_lds[r][c];
        dst[0] = v.x; dst[1] = v.y; dst[2] = v.z; dst[3] = v.w;
    }
    __syncthreads();

    float acc[4][6];
#pragma unroll
    for (int q = 0; q < 4; ++q) {
        const int f = wid * 4 + q;
        acc[q][0] = b_ih[f];       // i_r
        acc[q][1] = b_ih[64 + f];  // i_z
        acc[q][2] = b_ih[128 + f]; // i_n
        acc[q][3] = b_hh[f];       // h_r
        acc[q][4] = b_hh[64 + f];  // h_z
        acc[q][5] = b_hh[128 + f]; // h_n
    }

    for (int kb = 0; kb < 16; ++kb) {
        const int k0 = kb * 4;
        float a0 = a_lds[lane][k0],     a1 = a_lds[lane][k0 + 1];
        float a2 = a_lds[lane][k0 + 2], a3 = a_lds[lane][k0 + 3];
        float h0 = h_lds[lane][k0],     h1 = h_lds[lane][k0 + 1];
        float h2 = h_lds[lane][k0 + 2], h3 = h_lds[lane][k0 + 3];
#pragma unroll
        for (int q = 0; q < 4; ++q) {
            const int f = wid * 4 + q;
            const float* wr = Wic + (size_t)f * 64 + k0;          // uniform -> s_load
            const float* wz = Wic + (size_t)(64 + f) * 64 + k0;
            const float* wn = Wic + (size_t)(128 + f) * 64 + k0;
            const float* vr = whh + (size_t)f * 64 + k0;
            const float* vz = whh + (size_t)(64 + f) * 64 + k0;
            const float* vn = whh + (size_t)(128 + f) * 64 + k0;
            acc[q][0] = fmaf(a0, wr[0], acc[q][0]); acc[q][0] = fmaf(a1, wr[1], acc[q][0]);
            acc[q][0] = fmaf(a2, wr[2], acc[q][0]); acc[q][0] = fmaf(a3, wr[3], acc[q][0]);
            acc[q][1] = fmaf(a0, wz[0], acc[q][1]); acc[q][1] = fmaf(a1, wz[1], acc[q][1]);
            acc[q][1] = fmaf(a2, wz[2], acc[q][1]); acc[q][1] = fmaf(a3, wz[3], acc[q][1]);
            acc[q][2] = fmaf(a0, wn[0], acc[q][2]); acc[q][2] = fmaf(a1, wn[1], acc[q][2]);
            acc[q][2] = fmaf(a2, wn[2], acc[q][2]); acc[q][2] = fmaf(a3, wn[3], acc[q][2]);
            acc[q][3] = fmaf(h0, vr[0], acc[q][3]); acc[q][3] = fmaf(h1, vr[1], acc[q][3]);
            acc[q][3] = fmaf(h2, vr[2], acc[q][3]); acc[q][3] = fmaf(h3, vr[3], acc[q][3]);
            acc[q][4] = fmaf(h0, vz[0], acc[q][4]); acc[q][4] = fmaf(h1, vz[1], acc[q][4]);
            acc[q][4] = fmaf(h2, vz[2], acc[q][4]); acc[q][4] = fmaf(h3, vz[3], acc[q][4]);
            acc[q][5] = fmaf(h0, vn[0], acc[q][5]); acc[q][5] = fmaf(h1, vn[1], acc[q][5]);
            acc[q][5] = fmaf(h2, vn[2], acc[q][5]); acc[q][5] = fmaf(h3, vn[3], acc[q][5]);
        }
    }

    // gates + stage result in LDS
#pragma unroll
    for (int q = 0; q < 4; ++q) {
        const int f = wid * 4 + q;
        float hold = h_lds[lane][f];
        float r  = 1.f / (1.f + __expf(-(acc[q][0] + acc[q][3])));
        float z  = 1.f / (1.f + __expf(-(acc[q][1] + acc[q][4])));
        float x2 = acc[q][2] + r * acc[q][5];
        float nn = 1.f - 2.f / (__expf(2.f * x2) + 1.f);  // tanh, inf-safe
        o_lds[lane][f] = (1.f - z) * nn + z * hold;
    }
    __syncthreads();

    // coalesced write-back: 1024 float4, 1 per thread
    {
        int e = tid;
        int r = e >> 4, c = (e & 15) * 4;
        int node = n0 + r;
        if (node < n_nodes) {
            float4 v = make_float4(o_lds[r][c], o_lds[r][c + 1],
                                   o_lds[r][c + 2], o_lds[r][c + 3]);
            reinterpret_cast<float4*>(h + (size_t)node * HID)[e & 15] = v;
        }
    }
}

// ---------------------------------------------------------------------------
// out = softmax(h @ w2.T + b2)  wave per node; lane<40 = class; w2 in VGPRs
// ---------------------------------------------------------------------------
__global__ __launch_bounds__(256) void k_out(
    const float* __restrict__ h, const float* __restrict__ w2,
    const float* __restrict__ b2, float* __restrict__ out, int n_nodes)
{
    const int tid = threadIdx.x, lane = tid & 63;
    float wreg[64];
    float bias = 0.f;
    if (lane < NCLASS) {
#pragma unroll
        for (int k = 0; k < 64; k += 4) {
            float4 v = *reinterpret_cast<const float4*>(&w2[lane * HID + k]);
            wreg[k] = v.x; wreg[k + 1] = v.y; wreg[k + 2] = v.z; wreg[k + 3] = v.w;
        }
        bias = b2[lane];
    } else {
#pragma unroll
        for (int k = 0; k < 64; ++k) wreg[k] = 0.f;
    }
    int wid    = (blockIdx.x * blockDim.x + tid) >> 6;
    int nwaves = (gridDim.x * blockDim.x) >> 6;
    for (int node = wid; node < n_nodes; node += nwaves) {
        const float4* r4 = reinterpret_cast<const float4*>(h + (size_t)node * HID);
        float a0 = bias, a1 = 0.f, a2 = 0.f, a3 = 0.f;
#pragma unroll
        for (int kq = 0; kq < 16; ++kq) {
            float4 v = r4[kq];
            a0 = fmaf(v.x, wreg[4 * kq + 0], a0);
            a1 = fmaf(v.y, wreg[4 * kq + 1], a1);
            a2 = fmaf(v.z, wreg[4 * kq + 2], a2);
            a3 = fmaf(v.w, wreg[4 * kq + 3], a3);
        }
        float lg = (lane < NCLASS) ? (a0 + a1) + (a2 + a3) : -INFINITY;
        float m = lg;
#pragma unroll
        for (int off = 32; off > 0; off >>= 1) m = fmaxf(m, __shfl_xor(m, off, 64));
        float p = (lane < NCLASS) ? __expf(lg - m) : 0.f;
        float s = p;
#pragma unroll
        for (int off = 32; off > 0; off >>= 1) s += __shfl_xor(s, off, 64);
        if (lane < NCLASS) out[(size_t)node * NCLASS + lane] = p / s;
    }
}

// ---------------------------------------------------------------------------
extern "C" void kernel_launch(void* const* d_in, const int* in_sizes, int n_in,
                              void* d_out, int out_size, void* d_ws, size_t ws_size,
                              hipStream_t stream)
{
    const float* x    = (const float*)d_in[0];
    const int*   ei   = (const int*)d_in[1];    // int32 per harness contract
    const float* w1   = (const float*)d_in[2];
    const float* b1   = (const float*)d_in[3];
    const float* gg_w = (const float*)d_in[4];
    const float* w_ih = (const float*)d_in[5];
    const float* w_hh = (const float*)d_in[6];
    const float* b_ih = (const float*)d_in[7];
    const float* b_hh = (const float*)d_in[8];
    const float* w2   = (const float*)d_in[9];
    const float* b2   = (const float*)d_in[10];
    float*       out  = (float*)d_out;

    const int n = in_sizes[0] / NFEAT;   // 200000
    const int E = in_sizes[1] / 2;       // 1200000

    // workspace carve (~110 MB), 256-B aligned slots
    char* ws0 = (char*)d_ws;
    char* ws  = ws0;
    auto carve = [&](size_t bytes) {
        char* p = ws;
        ws += (bytes + 255) & ~(size_t)255;
        return p;
    };
    float* h       = (float*)carve((size_t)n * HID * 4);
    float* ah      = (float*)carve((size_t)n * HID * 4);
    float* Wic     = (float*)carve((size_t)NUM_LAYERS * 192 * 64 * 4);
    int*   row_ptr = (int*)carve((size_t)(n + 1) * 4);
    int*   col_src = (int*)carve((size_t)E * 4);
    int*   cnt     = (int*)carve((size_t)n * 4);
    int*   cursor  = (int*)carve((size_t)n * 4);
    int*   btot    = (int*)carve(8192);

    const int nb = (n + SCAN_C - 1) / SCAN_C;

    hipMemsetAsync(cnt, 0, (size_t)n * 4, stream);
    k_wic<<<(NUM_LAYERS * 192 * 64 + 255) / 256, 256, 0, stream>>>(gg_w, w_ih, Wic);
    k_lin1<<<2048, 256, 0, stream>>>(x, w1, b1, h, n);
    k_hist<<<(E + 255) / 256, 256, 0, stream>>>(ei, cnt, E);
    k_scan1<<<nb, 512, 0, stream>>>(cnt, btot, n);
    k_scan2<<<1, 1024, 0, stream>>>(btot, nb);
    k_scan3<<<nb, 512, 0, stream>>>(cnt, btot, row_ptr, cursor, n);
    k_fill<<<(E + 255) / 256, 256, 0, stream>>>(ei, cursor, col_src, E);

    const int ngrp = (n + 63) / 64;  // 3125
    for (int l = 0; l < NUM_LAYERS; ++l) {
        k_agg<<<2048, 256, 0, stream>>>(h, row_ptr, col_src, ah, n);
        k_gru6<<<ngrp, G6_THREADS, 0, stream>>>(ah, h, Wic + (size_t)l * 192 * 64,
                                                w_hh, b_ih, b_hh, n);
    }
    k_out<<<2048, 256, 0, stream>>>(h, w2, b2, out, n);
}